// Round 1
// baseline (1013.239 us; speedup 1.0000x reference)
//
#include <hip/hip_runtime.h>
#include <math.h>

// VQ nearest-codebook: X (N=131072, C=256) fp32, CB (K=1024, C=256) fp32.
// argmin_k ||x - e_k||^2 == argmin_k (e_k^2 - 2 x.e_k)  (x^2 constant per row)
// Outputs (concat in d_out, fp32): zq (N*256), indices-as-float (N).
//
// Compute-bound fp32 GEMM-like kernel: 68.7 GFLOP on the vector ALU
// (no fp32 MFMA on CDNA4). Tile: BM=64 pts x BN=128 codes, BK=32 C-chunk
// in LDS, 8x4 register tile per thread (256 threads).

#define BM 64
#define BN 128
#define BK 32
#define TM 8
#define TN 4
#define PA 68    // BM+4: pad keeps 16B alignment (68%4==0) and breaks bank conflicts
#define PB 132   // BN+4

// e2[k] = sum_c cb[k][c]^2 — one wave per code row.
__global__ __launch_bounds__(256) void vq_esq(const float* __restrict__ cb,
                                              float* __restrict__ e2, int K) {
    int wave = threadIdx.x >> 6;
    int lane = threadIdx.x & 63;
    int code = blockIdx.x * 4 + wave;
    if (code >= K) return;
    float4 v = ((const float4*)(cb + (size_t)code * 256))[lane];
    float s = v.x * v.x + v.y * v.y + v.z * v.z + v.w * v.w;
#pragma unroll
    for (int off = 32; off > 0; off >>= 1) s += __shfl_down(s, off, 64);
    if (lane == 0) e2[code] = s;
}

__global__ __launch_bounds__(256) void vq_main(
    const float* __restrict__ x, const float* __restrict__ cb,
    const float* __restrict__ e2, float* __restrict__ zq,
    float* __restrict__ idx_out, int K) {
    // sA|sB staging; same memory reused for the final argmin reduction.
    __shared__ float smem[BK * PA + BK * PB];   // 2176 + 4224 floats = 25.6 KB
    float* sA = smem;
    float* sB = smem + BK * PA;
    __shared__ int sWin[BM];

    const int tid = threadIdx.x;
    const int tx = tid & 31;   // code group: codes tx*4..tx*4+3 within tile
    const int ty = tid >> 5;   // point group: points ty*8..ty*8+7

    const size_t baseP = (size_t)blockIdx.x * BM;

    // staging maps
    const int ar = tid >> 2, aq = tid & 3;   // A: 64 rows, 2 float4 each {aq, aq+4}
    const int br = tid >> 1, bh = tid & 1;   // B: 128 rows, 4 float4 each {bh,bh+2,bh+4,bh+6}

    float bestD[TM];
    int bestI[TM];
#pragma unroll
    for (int i = 0; i < TM; ++i) { bestD[i] = INFINITY; bestI[i] = 0; }

    for (int kt = 0; kt < K; kt += BN) {
        float acc[TM][TN];
#pragma unroll
        for (int i = 0; i < TM; ++i)
#pragma unroll
            for (int j = 0; j < TN; ++j) acc[i][j] = 0.0f;

        for (int ck = 0; ck < 256; ck += BK) {
            // global loads (issue before the barrier so they overlap)
            const float* xr = x + (baseP + ar) * 256 + ck;
            float4 a0 = *(const float4*)(xr + aq * 4);
            float4 a1 = *(const float4*)(xr + (aq + 4) * 4);
            const float* cr = cb + (size_t)(kt + br) * 256 + ck;
            float4 b0 = *(const float4*)(cr + bh * 4);
            float4 b1 = *(const float4*)(cr + (bh + 2) * 4);
            float4 b2 = *(const float4*)(cr + (bh + 4) * 4);
            float4 b3 = *(const float4*)(cr + (bh + 6) * 4);

            __syncthreads();   // previous chunk fully consumed
            {
                float av0[4] = {a0.x, a0.y, a0.z, a0.w};
                float av1[4] = {a1.x, a1.y, a1.z, a1.w};
#pragma unroll
                for (int j = 0; j < 4; ++j) {
                    sA[(aq * 4 + j) * PA + ar] = av0[j];
                    sA[((aq + 4) * 4 + j) * PA + ar] = av1[j];
                }
                float4 bq[4] = {b0, b1, b2, b3};
#pragma unroll
                for (int k = 0; k < 4; ++k) {
                    float bv[4] = {bq[k].x, bq[k].y, bq[k].z, bq[k].w};
#pragma unroll
                    for (int j = 0; j < 4; ++j)
                        sB[((bh + 2 * k) * 4 + j) * PB + br] = bv[j];
                }
            }
            __syncthreads();

#pragma unroll 8
            for (int kk = 0; kk < BK; ++kk) {
                float4 aA = *(const float4*)(sA + kk * PA + ty * TM);
                float4 aB = *(const float4*)(sA + kk * PA + ty * TM + 4);
                float4 bb = *(const float4*)(sB + kk * PB + tx * TN);
                float av[8] = {aA.x, aA.y, aA.z, aA.w, aB.x, aB.y, aB.z, aB.w};
                float bv[4] = {bb.x, bb.y, bb.z, bb.w};
#pragma unroll
                for (int i = 0; i < TM; ++i)
#pragma unroll
                    for (int j = 0; j < TN; ++j)
                        acc[i][j] = fmaf(av[i], bv[j], acc[i][j]);
            }
        }

        // epilogue for this code tile: d = e2[k] - 2*dot  (2*acc is exact)
        float4 e4 = *(const float4*)(e2 + kt + tx * TN);
        float ev[4] = {e4.x, e4.y, e4.z, e4.w};
#pragma unroll
        for (int j = 0; j < TN; ++j) {
            int code = kt + tx * TN + j;
#pragma unroll
            for (int i = 0; i < TM; ++i) {
                float d = ev[j] - 2.0f * acc[i][j];
                if (d < bestD[i]) { bestD[i] = d; bestI[i] = code; }
                // within a thread, codes strictly increase -> '<' keeps lowest idx
            }
        }
    }

    // cross-thread argmin over the 32 tx groups, per point
    __syncthreads();
    float* sD = smem;                       // 64*32 floats
    int* sI = (int*)(smem + BM * 32);       // 64*32 ints
#pragma unroll
    for (int i = 0; i < TM; ++i) {
        int p = ty * TM + i;
        sD[p * 32 + tx] = bestD[i];
        sI[p * 32 + tx] = bestI[i];
    }
    __syncthreads();
    if (tid < BM) {
        float bd = INFINITY;
        int bi = 0x7fffffff;
        for (int t = 0; t < 32; ++t) {
            float d = sD[tid * 32 + t];
            int ii = sI[tid * 32 + t];
            if (d < bd || (d == bd && ii < bi)) { bd = d; bi = ii; }
        }
        sWin[tid] = bi;
        idx_out[baseP + tid] = (float)bi;   // indices stored as float in d_out
    }
    __syncthreads();

    // gather winning codebook rows -> zq (codebook is L2/L3-hot)
    int wv = tid >> 6, ln = tid & 63;
    for (int p = wv * 16; p < wv * 16 + 16; ++p) {
        int w = sWin[p];
        float4 v = ((const float4*)(cb + (size_t)w * 256))[ln];
        ((float4*)(zq + (baseP + p) * 256))[ln] = v;
    }
}

extern "C" void kernel_launch(void* const* d_in, const int* in_sizes, int n_in,
                              void* d_out, int out_size, void* d_ws, size_t ws_size,
                              hipStream_t stream) {
    const float* x = (const float*)d_in[0];
    const float* cb = (const float*)d_in[1];
    int N = in_sizes[0] / 256;   // 131072 points
    int K = in_sizes[1] / 256;   // 1024 codes

    float* zq = (float*)d_out;
    float* idxf = zq + (size_t)N * 256;
    float* e2 = (float*)d_ws;    // K floats of scratch

    vq_esq<<<dim3((K + 3) / 4), dim3(256), 0, stream>>>(cb, e2, K);
    vq_main<<<dim3(N / BM), dim3(256), 0, stream>>>(x, cb, e2, zq, idxf, K);
}

// Round 2
// 754.151 us; speedup vs baseline: 1.3435x; 1.3435x over previous
//
#include <hip/hip_runtime.h>
#include <math.h>

// VQ nearest-codebook via split-bf16 MFMA + exact fp32 top-2 recheck.
// x (131072 x 256) fp32, cb (1024 x 256) fp32.
// dist = e2[k] - 2*dot (x^2 constant per point, argmin-invariant).
// dot approximated as xh*eh + xl*eh + xh*el (3-pass bf16 MFMA, fp32 acc),
// per-point top-2 candidates tracked, then exact fp32 recheck decides.
// Outputs (concat fp32): zq (N*256), indices-as-float (N).

typedef __attribute__((ext_vector_type(8))) short short8;   // 8 bf16 = 4 VGPR
typedef __attribute__((ext_vector_type(4))) float f32x4;

#define C_DIM 256
#define BM 128      // points per block
#define BN 128      // codes per kt tile (8 tiles cover K=1024)
#define BK 32       // contraction chunk
#define PP 40       // LDS row pitch (bf16 elems): 32 + 8 pad, 80 B = 5x16B

__device__ __forceinline__ unsigned short f2bf(float f) {
    unsigned u = __float_as_uint(f);
    return (unsigned short)((u + 0x7fffu + ((u >> 16) & 1u)) >> 16);
}

// e2[k] = exact fp32 sum of squares of codebook row k. One wave per row.
__global__ __launch_bounds__(256) void vq_esq(const float* __restrict__ cb,
                                              float* __restrict__ e2, int K) {
    int wave = threadIdx.x >> 6;
    int lane = threadIdx.x & 63;
    int code = blockIdx.x * 4 + wave;
    if (code >= K) return;
    float4 v = ((const float4*)(cb + (size_t)code * C_DIM))[lane];
    float s = v.x * v.x + v.y * v.y + v.z * v.z + v.w * v.w;
#pragma unroll
    for (int off = 32; off > 0; off >>= 1) s += __shfl_down(s, off, 64);
    if (lane == 0) e2[code] = s;
}

__global__ __launch_bounds__(256) void vq_mfma(
    const float* __restrict__ x, const float* __restrict__ cb,
    const float* __restrict__ e2, float* __restrict__ zq,
    float* __restrict__ idxf) {

    __shared__ char smem_raw[40960];
    short* sAh = (short*)(smem_raw);            // [128][PP]
    short* sAl = (short*)(smem_raw + 10240);
    short* sBh = (short*)(smem_raw + 20480);
    short* sBl = (short*)(smem_raw + 30720);

    const int tid = threadIdx.x;
    const int lane = tid & 63;
    const int w = tid >> 6;          // wave id 0..3
    const int ln = lane & 15;        // column-within-16 (n / row-select)
    const int q = lane >> 4;         // k-octet select
    const int wm = (w & 1) * 64;     // wave m-offset in 128-pt tile
    const int wn = (w >> 1) * 64;    // wave n-offset in 128-code tile
    const size_t basep = (size_t)blockIdx.x * BM;

    const int srow = tid >> 1;       // staging row 0..127
    const int kh = tid & 1;          // staging k-half (16 elems each)

    // per-lane top-2 state for 16 points (mt,reg)
    float d1s[16], d2s[16];
    int c1s[16], c2s[16];
#pragma unroll
    for (int s = 0; s < 16; ++s) { d1s[s] = 1e30f; d2s[s] = 1e30f; c1s[s] = 0; c2s[s] = 1; }

    for (int kt = 0; kt < 8; ++kt) {
        f32x4 acc[4][4];
#pragma unroll
        for (int mt = 0; mt < 4; ++mt)
#pragma unroll
            for (int nt = 0; nt < 4; ++nt)
#pragma unroll
                for (int r = 0; r < 4; ++r) acc[mt][nt][r] = 0.0f;

        int cnv[4];
        float e2v[4];
#pragma unroll
        for (int nt = 0; nt < 4; ++nt) {
            cnv[nt] = kt * BN + wn + nt * 16 + ln;
            e2v[nt] = e2[cnv[nt]];
        }

        for (int ck = 0; ck < C_DIM; ck += BK) {
            // ---- global loads + fp32->bf16 hi/lo split (before barrier) ----
            const float* xr = x + (basep + srow) * C_DIM + ck + kh * 16;
            const float* cr = cb + (size_t)(kt * BN + srow) * C_DIM + ck + kh * 16;
            float4 xa[4], ba[4];
#pragma unroll
            for (int i = 0; i < 4; ++i) { xa[i] = ((const float4*)xr)[i]; ba[i] = ((const float4*)cr)[i]; }

            short8 Ah[2], Al[2], Bh[2], Bl[2];
#pragma unroll
            for (int g = 0; g < 2; ++g) {
#pragma unroll
                for (int i = 0; i < 8; ++i) {
                    float fa = ((const float*)&xa[g * 2])[i];
                    float fb = ((const float*)&ba[g * 2])[i];
                    unsigned short ha = f2bf(fa);
                    unsigned short hb = f2bf(fb);
                    Ah[g][i] = (short)ha;
                    Bh[g][i] = (short)hb;
                    Al[g][i] = (short)f2bf(fa - __uint_as_float((unsigned)ha << 16));
                    Bl[g][i] = (short)f2bf(fb - __uint_as_float((unsigned)hb << 16));
                }
            }

            __syncthreads();   // previous chunk fully consumed
            {
                int di = srow * PP + kh * 16;
                *(short8*)(sAh + di) = Ah[0]; *(short8*)(sAh + di + 8) = Ah[1];
                *(short8*)(sAl + di) = Al[0]; *(short8*)(sAl + di + 8) = Al[1];
                *(short8*)(sBh + di) = Bh[0]; *(short8*)(sBh + di + 8) = Bh[1];
                *(short8*)(sBl + di) = Bl[0]; *(short8*)(sBl + di + 8) = Bl[1];
            }
            __syncthreads();

            // ---- fragments ----
            short8 ah[4], al[4], bh[4], bl[4];
#pragma unroll
            for (int mt = 0; mt < 4; ++mt) {
                int ra = (wm + mt * 16 + ln) * PP + q * 8;
                ah[mt] = *(const short8*)(sAh + ra);
                al[mt] = *(const short8*)(sAl + ra);
            }
#pragma unroll
            for (int nt = 0; nt < 4; ++nt) {
                int rb = (wn + nt * 16 + ln) * PP + q * 8;
                bh[nt] = *(const short8*)(sBh + rb);
                bl[nt] = *(const short8*)(sBl + rb);
            }

            // ---- 48 MFMAs: hh pass, lh pass, hl pass (max ILP per acc) ----
#pragma unroll
            for (int mt = 0; mt < 4; ++mt)
#pragma unroll
                for (int nt = 0; nt < 4; ++nt)
                    acc[mt][nt] = __builtin_amdgcn_mfma_f32_16x16x32_bf16(ah[mt], bh[nt], acc[mt][nt], 0, 0, 0);
#pragma unroll
            for (int mt = 0; mt < 4; ++mt)
#pragma unroll
                for (int nt = 0; nt < 4; ++nt)
                    acc[mt][nt] = __builtin_amdgcn_mfma_f32_16x16x32_bf16(al[mt], bh[nt], acc[mt][nt], 0, 0, 0);
#pragma unroll
            for (int mt = 0; mt < 4; ++mt)
#pragma unroll
                for (int nt = 0; nt < 4; ++nt)
                    acc[mt][nt] = __builtin_amdgcn_mfma_f32_16x16x32_bf16(ah[mt], bl[nt], acc[mt][nt], 0, 0, 0);
        }

        // ---- per-kt top-2 update (branchless, 8 insts/elem) ----
#pragma unroll
        for (int mt = 0; mt < 4; ++mt)
#pragma unroll
            for (int nt = 0; nt < 4; ++nt)
#pragma unroll
                for (int r = 0; r < 4; ++r) {
                    float d = fmaf(-2.0f, acc[mt][nt][r], e2v[nt]);
                    int s = mt * 4 + r;
                    int cn = cnv[nt];
                    bool lt2 = d < d2s[s];
                    bool lt1 = d < d1s[s];
                    float td = lt1 ? d1s[s] : d;
                    int tc = lt1 ? c1s[s] : cn;
                    d2s[s] = lt2 ? td : d2s[s];
                    c2s[s] = lt2 ? tc : c2s[s];
                    d1s[s] = lt1 ? d : d1s[s];
                    c1s[s] = lt1 ? cn : c1s[s];
                }
    }

    // ---- butterfly top-2 merge across the 16 ln-lanes (codes disjoint) ----
#pragma unroll
    for (int m = 1; m <= 8; m <<= 1) {
#pragma unroll
        for (int s = 0; s < 16; ++s) {
            float od1 = __shfl_xor(d1s[s], m);
            int oc1 = __shfl_xor(c1s[s], m);
            float od2 = __shfl_xor(d2s[s], m);
            int oc2 = __shfl_xor(c2s[s], m);
            bool t = (od1 < d1s[s]) || (od1 == d1s[s] && oc1 < c1s[s]);
            float hd = t ? d1s[s] : od1;   // loser of firsts
            int hc = t ? c1s[s] : oc1;
            float nd1 = t ? od1 : d1s[s];
            int nc1 = t ? oc1 : c1s[s];
            bool u = od2 < d2s[s];
            float md = u ? od2 : d2s[s];   // min of seconds
            int mc = u ? oc2 : c2s[s];
            bool v2 = (hd < md) || (hd == md && hc < mc);
            d2s[s] = v2 ? hd : md;
            c2s[s] = v2 ? hc : mc;
            d1s[s] = nd1;
            c1s[s] = nc1;
        }
    }

    __syncthreads();   // staging LDS reads done everywhere; safe to reuse
    float* mD1 = (float*)(smem_raw);
    int* mC1 = (int*)(smem_raw + 1024);
    float* mD2 = (float*)(smem_raw + 2048);
    int* mC2 = (int*)(smem_raw + 3072);
    int* sCand = (int*)(smem_raw + 4096);   // [128][2]
    int* sWin = (int*)(smem_raw + 5120);    // [128]

    if (ln == 0) {
        int half = w >> 1;
#pragma unroll
        for (int mt = 0; mt < 4; ++mt)
#pragma unroll
            for (int r = 0; r < 4; ++r) {
                int s = mt * 4 + r;
                int p = wm + mt * 16 + q * 4 + r;
                mD1[p * 2 + half] = d1s[s];
                mC1[p * 2 + half] = c1s[s];
                mD2[p * 2 + half] = d2s[s];
                mC2[p * 2 + half] = c2s[s];
            }
    }
    __syncthreads();

    // ---- per-point merge of the two code-halves -> 2 candidates ----
    if (tid < BM) {
        float da1 = mD1[tid * 2], db1 = mD1[tid * 2 + 1];
        int ca1 = mC1[tid * 2], cb1i = mC1[tid * 2 + 1];
        float da2 = mD2[tid * 2], db2 = mD2[tid * 2 + 1];
        int ca2 = mC2[tid * 2], cb2i = mC2[tid * 2 + 1];
        bool t = (db1 < da1) || (db1 == da1 && cb1i < ca1);
        int c1f = t ? cb1i : ca1;
        float xd1 = t ? db2 : da2;
        int xc1 = t ? cb2i : ca2;
        float xd2 = t ? da1 : db1;
        int xc2 = t ? ca1 : cb1i;
        bool u = (xd1 < xd2) || (xd1 == xd2 && xc1 < xc2);
        int c2f = u ? xc1 : xc2;
        sCand[tid * 2] = c1f;
        sCand[tid * 2 + 1] = c2f;
    }
    __syncthreads();

    // ---- exact fp32 recheck: one thread per (point, candidate) ----
    {
        int p = tid >> 1;
        int cc = sCand[tid];
        const float4* xr4 = (const float4*)(x + (basep + p) * C_DIM);
        const float4* cr4 = (const float4*)(cb + (size_t)cc * C_DIM);
        float4 s4 = {0.f, 0.f, 0.f, 0.f};
#pragma unroll 8
        for (int j = 0; j < 64; ++j) {
            float4 a = xr4[j], b = cr4[j];
            s4.x = fmaf(a.x, b.x, s4.x);
            s4.y = fmaf(a.y, b.y, s4.y);
            s4.z = fmaf(a.z, b.z, s4.z);
            s4.w = fmaf(a.w, b.w, s4.w);
        }
        float dot = (s4.x + s4.y) + (s4.z + s4.w);
        float d = fmaf(-2.0f, dot, e2[cc]);
        float od = __shfl_xor(d, 1);
        int oc = __shfl_xor(cc, 1);
        int winc = (d < od || (d == od && cc < oc)) ? cc : oc;
        if ((tid & 1) == 0) {
            sWin[p] = winc;
            idxf[basep + p] = (float)winc;
        }
    }
    __syncthreads();

    // ---- gather winning codebook rows -> zq (cb is L2-hot) ----
#pragma unroll 4
    for (int p = w * 32; p < w * 32 + 32; ++p) {
        int cc = sWin[p];
        float4 v = ((const float4*)(cb + (size_t)cc * C_DIM))[lane];
        ((float4*)(zq + (basep + p) * C_DIM))[lane] = v;
    }
}

extern "C" void kernel_launch(void* const* d_in, const int* in_sizes, int n_in,
                              void* d_out, int out_size, void* d_ws, size_t ws_size,
                              hipStream_t stream) {
    const float* x = (const float*)d_in[0];
    const float* cb = (const float*)d_in[1];
    int N = in_sizes[0] / C_DIM;   // 131072
    int K = in_sizes[1] / C_DIM;   // 1024

    float* zq = (float*)d_out;
    float* idxf = zq + (size_t)N * C_DIM;
    float* e2 = (float*)d_ws;      // K floats of scratch

    vq_esq<<<dim3((K + 3) / 4), dim3(256), 0, stream>>>(cb, e2, K);
    vq_mfma<<<dim3(N / BM), dim3(256), 0, stream>>>(x, cb, e2, zq, idxf);
}